// Round 9
// baseline (395.775 us; speedup 1.0000x reference)
//
#include <hip/hip_runtime.h>
#include <float.h>
#include <math.h>

#define NROWS 512
#define DIM 1024
#define NTRAIN 100000
#define MAXK 200
#define NCLS 1000
#define CAP 512          // finalize working set
#define CAP2 1024        // candidate list per row (expected ~260)
#define INV_T (1.0f/0.07f)
#define NKS (DIM/32)     // 32 K-steps of BK=32
#define NTILE 784        // ceil(100000/128)
#define NPAD (NTILE*128) // 100352 padded sims stride
#define MARGIN 3.0f      // ~20 sigma of bf16-RTZ sim error + storage ulp
#define HBINS 2048
#define HLO (-160.0f)
#define HSC 6.4f         // bins of width 0.15625 over [-160,160)

typedef short s16x8 __attribute__((ext_vector_type(8)));
typedef unsigned short u16x8 __attribute__((ext_vector_type(8)));
typedef unsigned int u32x4 __attribute__((ext_vector_type(4)));
typedef float f32x4 __attribute__((ext_vector_type(4)));

__device__ __forceinline__ void gl_lds16(const void* g, void* l) {
    __builtin_amdgcn_global_load_lds(
        (const __attribute__((address_space(1))) unsigned int*)g,
        (__attribute__((address_space(3))) unsigned int*)l, 16, 0, 0);
}
__device__ __forceinline__ unsigned short f2bf(float x) {   // RTNE
    unsigned u = __float_as_uint(x);
    return (unsigned short)((u + 0x7FFFu + ((u >> 16) & 1u)) >> 16);
}
__device__ __forceinline__ float bf2f(unsigned short b) {
    return __uint_as_float(((unsigned)b) << 16);
}

// ---------------- fp32 -> bf16 (A only; B fused into GEMM) ----------------
__global__ __launch_bounds__(256) void convert_bf16(
    const float* __restrict__ in, unsigned short* __restrict__ out, long long n)
{
    long long i0 = ((long long)blockIdx.x * 256 + threadIdx.x) * 8;
    long long stride = (long long)gridDim.x * 2048;
    for (long long i = i0; i < n; i += stride) {
        float4 v0 = *reinterpret_cast<const float4*>(&in[i]);
        float4 v1 = *reinterpret_cast<const float4*>(&in[i + 4]);
        u16x8 o;
        o[0] = f2bf(v0.x); o[1] = f2bf(v0.y); o[2] = f2bf(v0.z); o[3] = f2bf(v0.w);
        o[4] = f2bf(v1.x); o[5] = f2bf(v1.y); o[6] = f2bf(v1.z); o[7] = f2bf(v1.w);
        *reinterpret_cast<u16x8*>(&out[i]) = o;
    }
}

// ---------------- fused GEMM: A via global_load_lds, B reg-staged fp32->bf16 ----------------
// 128x128 tile, BK=32, 4 waves. 3 bufs x (A 8KB + B 8KB) = 48KB -> 3 blocks/CU.
// Both A and B use the PROVEN zero-conflict LDS layout: granule(rr,q) at
// chunk = rr*4 + (q ^ ((rr>>1)&3)), 16B each (r5-r7: SQ_LDS_BANK_CONFLICT == 0).
// B: 4 global_load_dwordx4 fp32 -> regs (2-step lead) -> 8 v_perm RTZ pack ->
// 2 ds_write_b128 (write-side convert, each element converted once per block).
// Counted vmcnt(6): each step's {2 A-glds + 4 B-glb} stays in flight one step.
__global__ __launch_bounds__(256) void gemm_fused(
    const unsigned short* __restrict__ Ab, const float* __restrict__ B,
    unsigned short* __restrict__ simsb)
{
    __shared__ __align__(16) unsigned short sm[3][2][4096];  // [buf][A,B][8KB]
    const int tid = threadIdx.x;
    const int lane = tid & 63;
    const int wave = tid >> 6;

    // bijective XCD swizzle (grid % 8 == 0), m-tile fastest for B-panel L2 reuse
    const int nwg = gridDim.x;
    const int wg = (blockIdx.x & 7) * (nwg >> 3) + (blockIdx.x >> 3);
    const int mt = wg & 3, nt = wg >> 2;
    const int m0 = mt * 128, n0 = nt * 128;
    const int wm = wave >> 1, wn = wave & 1;

    // A staging (global_load_lds): instr i covers chunks wave*64 + i*256 + lane
    size_t gA[2];
    #pragma unroll
    for (int i = 0; i < 2; ++i) {
        int c = wave * 64 + i * 256 + lane;
        int rr = c >> 2, q = c & 3;
        int slot = q ^ ((rr >> 1) & 3);
        gA[i] = (size_t)(m0 + rr) * DIM + slot * 8;   // bf16 elements
    }
    const int ldsA0 = (wave * 64) * 16;
    const int ldsA1 = (wave * 64 + 256) * 16;

    // B reg staging: thread covers granules c0 = tid, c1 = tid + 256
    const int rr0 = tid >> 2, q0 = tid & 3;
    const int rr1 = rr0 + 64;
    int brow0 = n0 + rr0; if (brow0 > NTRAIN - 1) brow0 = NTRAIN - 1;
    int brow1 = n0 + rr1; if (brow1 > NTRAIN - 1) brow1 = NTRAIN - 1;
    const size_t gb0 = (size_t)brow0 * DIM + q0 * 8;   // fp32 elements
    const size_t gb1 = (size_t)brow1 * DIM + q0 * 8;
    const int lo0 = (rr0 * 4 + (q0 ^ ((rr0 >> 1) & 3))) * 16;  // byte off in B region
    const int lo1 = (rr1 * 4 + (q0 ^ ((rr1 >> 1) & 3))) * 16;

    f32x4 acc[4][4] = {};
    u32x4 RA[2][2], RB[2][2];   // named stages (static indexing, rule #20)

    auto stageA = [&](int b, int k0) {
        char* base = (char*)&sm[b][0][0];
        gl_lds16(Ab + gA[0] + k0, base + ldsA0);
        gl_lds16(Ab + gA[1] + k0, base + ldsA1);
    };

#define LOADB(R, K0)                                                           \
    {                                                                          \
        R[0][0] = *reinterpret_cast<const u32x4*>(B + gb0 + (K0));             \
        R[0][1] = *reinterpret_cast<const u32x4*>(B + gb0 + (K0) + 4);         \
        R[1][0] = *reinterpret_cast<const u32x4*>(B + gb1 + (K0));             \
        R[1][1] = *reinterpret_cast<const u32x4*>(B + gb1 + (K0) + 4);         \
    }
#define WRITEB(BI, R)                                                          \
    {                                                                          \
        char* dstB = (char*)&sm[BI][1][0];                                     \
        u32x4 p0 = { __builtin_amdgcn_perm(R[0][0][1], R[0][0][0], 0x07060302u), \
                     __builtin_amdgcn_perm(R[0][0][3], R[0][0][2], 0x07060302u), \
                     __builtin_amdgcn_perm(R[0][1][1], R[0][1][0], 0x07060302u), \
                     __builtin_amdgcn_perm(R[0][1][3], R[0][1][2], 0x07060302u) }; \
        *reinterpret_cast<u32x4*>(dstB + lo0) = p0;                            \
        u32x4 p1 = { __builtin_amdgcn_perm(R[1][0][1], R[1][0][0], 0x07060302u), \
                     __builtin_amdgcn_perm(R[1][0][3], R[1][0][2], 0x07060302u), \
                     __builtin_amdgcn_perm(R[1][1][1], R[1][1][0], 0x07060302u), \
                     __builtin_amdgcn_perm(R[1][1][3], R[1][1][2], 0x07060302u) }; \
        *reinterpret_cast<u32x4*>(dstB + lo1) = p1;                            \
    }

    const int qq = lane >> 4;
    const int r16 = lane & 15;

    // prologue: A(0),A(1) glds; B(0)->RA, B(1)->RB; drain through B(0); write B(0)
    stageA(0, 0);
    stageA(1, 32);
    LOADB(RA, 0)
    LOADB(RB, 32)
    asm volatile("s_waitcnt vmcnt(4)" ::: "memory");   // leaves B(1)'s 4
    __builtin_amdgcn_sched_barrier(0);
    WRITEB(0, RA)
    asm volatile("s_waitcnt lgkmcnt(0)" ::: "memory");
    __builtin_amdgcn_s_barrier();

    // step T: load B(T+2) into RL, write B(T+1) from RW, compute buf T%3.
    // FIFO at vmcnt(6): drains A(T+1),B(T+1) (issued at T-1), leaves A(T+2),B(T+2).
#define STEP(T, RL, RW)                                                        \
    {                                                                          \
        if ((T) + 2 < NKS) {                                                   \
            stageA(((T) + 2) % 3, ((T) + 2) * 32);                             \
            LOADB(RL, ((T) + 2) * 32)                                          \
            asm volatile("s_waitcnt vmcnt(6)" ::: "memory");                   \
        } else if ((T) + 1 < NKS) {                                            \
            asm volatile("s_waitcnt vmcnt(0)" ::: "memory");                   \
        }                                                                      \
        __builtin_amdgcn_sched_barrier(0);                                     \
        if ((T) + 1 < NKS) WRITEB(((T) + 1) % 3, RW)                           \
        const unsigned short* sa = &sm[(T) % 3][0][0];                         \
        const unsigned short* sb = &sm[(T) % 3][1][0];                         \
        s16x8 bv[4];                                                           \
        _Pragma("unroll")                                                      \
        for (int n = 0; n < 4; ++n) {                                          \
            int rr = wn * 64 + n * 16 + r16;                                   \
            int cch = rr * 4 + (qq ^ ((rr >> 1) & 3));                         \
            bv[n] = *reinterpret_cast<const s16x8*>(&sb[cch * 8]);             \
        }                                                                      \
        _Pragma("unroll")                                                      \
        for (int m = 0; m < 4; ++m) {                                          \
            int rr = wm * 64 + m * 16 + r16;                                   \
            int cch = rr * 4 + (qq ^ ((rr >> 1) & 3));                         \
            s16x8 av = *reinterpret_cast<const s16x8*>(&sa[cch * 8]);          \
            _Pragma("unroll")                                                  \
            for (int n = 0; n < 4; ++n)                                        \
                acc[m][n] = __builtin_amdgcn_mfma_f32_16x16x32_bf16(av, bv[n], acc[m][n], 0, 0, 0); \
        }                                                                      \
        asm volatile("s_waitcnt lgkmcnt(0)" ::: "memory");                     \
        __builtin_amdgcn_s_barrier();                                          \
    }

    for (int tt = 0; tt < NKS; tt += 2) {
        STEP(tt, RA, RB)        // even: B(T+2)->RA, write B(T+1) from RB
        STEP(tt + 1, RB, RA)    // odd:  B(T+2)->RB, write B(T+1) from RA
    }
#undef STEP
#undef LOADB
#undef WRITEB

    // epilogue: C/D layout col=lane&15, row=(lane>>4)*4+reg; bf16 store
    const int q4 = (lane >> 4) * 4;
    const int cL = lane & 15;
    #pragma unroll
    for (int m = 0; m < 4; ++m)
        #pragma unroll
        for (int j = 0; j < 4; ++j) {
            int orow = m0 + wm * 64 + m * 16 + q4 + j;
            unsigned short* dst = simsb + (size_t)orow * NPAD + n0 + wn * 64 + cL;
            #pragma unroll
            for (int n = 0; n < 4; ++n)
                dst[n * 16] = f2bf(acc[m][n][j]);
        }
}

// ---------------- per-row: flat histogram -> threshold-with-margin -> append ----------------
__global__ __launch_bounds__(512) void select_margin(
    const unsigned short* __restrict__ simsb, int* __restrict__ ci, int* __restrict__ cc)
{
    __shared__ int hist[4][HBINS];   // 32KB, 4 replicas to cut atomic collisions
    __shared__ float s_L;
    __shared__ int s_cnt;
    const int tid = threadIdx.x;
    const int r = blockIdx.x;
    const unsigned short* srow = simsb + (size_t)r * NPAD;

    for (int i = tid; i < 4 * HBINS; i += 512) hist[i >> 11][i & (HBINS - 1)] = 0;
    if (tid == 0) s_cnt = 0;
    __syncthreads();

    // NTRAIN % 8 == 0: loops never touch pad cols
    for (int i = tid * 8; i < NTRAIN; i += 4096) {
        u16x8 v = *reinterpret_cast<const u16x8*>(&srow[i]);
        #pragma unroll
        for (int j = 0; j < 8; ++j) {
            int b = (int)fminf(fmaxf((bf2f(v[j]) - HLO) * HSC, 0.0f), 2047.0f);
            atomicAdd(&hist[tid & 3][b], 1);
        }
    }
    __syncthreads();
    for (int i = tid; i < HBINS; i += 512)
        hist[0][i] += hist[1][i] + hist[2][i] + hist[3][i];
    __syncthreads();
    if (tid == 0) {
        int cum = 0, b = HBINS - 1;
        for (; b > 0; --b) { if (cum + hist[0][b] >= MAXK) break; cum += hist[0][b]; }
        s_L = HLO + (float)b / HSC - MARGIN;   // bin lower edge minus margin
    }
    __syncthreads();
    const float Lv = s_L;

    for (int i = tid * 8; i < NTRAIN; i += 4096) {
        u16x8 v = *reinterpret_cast<const u16x8*>(&srow[i]);
        #pragma unroll
        for (int j = 0; j < 8; ++j) {
            if (bf2f(v[j]) >= Lv) {
                int p = atomicAdd(&s_cnt, 1);
                if (p < CAP2) ci[(size_t)r * CAP2 + p] = i + j;
            }
        }
    }
    __syncthreads();
    if (tid == 0) cc[r] = min(s_cnt, CAP2);
}

// ---------------- exact fp32 recompute of candidate dots ----------------
__global__ __launch_bounds__(256) void exact_refine(
    const float* __restrict__ A, const float* __restrict__ B,
    const int* __restrict__ ci, const int* __restrict__ cc, float* __restrict__ ev)
{
    __shared__ float sa[DIM];
    const int tid = threadIdx.x;
    const int r = blockIdx.x >> 2;
    const int part = blockIdx.x & 3;
    *reinterpret_cast<float4*>(&sa[tid * 4]) =
        *reinterpret_cast<const float4*>(&A[(size_t)r * DIM + tid * 4]);
    __syncthreads();
    const int lane = tid & 63;
    const int wave = tid >> 6;
    const int w = part * 4 + wave;
    const int M = min(cc[r], CAP2);

    for (int i = w; i < M; i += 16) {
        int idx = ci[(size_t)r * CAP2 + i];
        const float* brow = B + (size_t)idx * DIM;
        float s = 0.f;
        #pragma unroll
        for (int j = 0; j < 4; ++j) {
            float4 bvv = *reinterpret_cast<const float4*>(&brow[j * 256 + lane * 4]);
            float4 avv = *reinterpret_cast<const float4*>(&sa[j * 256 + lane * 4]);
            s = fmaf(avv.x, bvv.x, s);
            s = fmaf(avv.y, bvv.y, s);
            s = fmaf(avv.z, bvv.z, s);
            s = fmaf(avv.w, bvv.w, s);
        }
        #pragma unroll
        for (int m = 32; m >= 1; m >>= 1) s += __shfl_xor(s, m);
        if (lane == 0) ev[(size_t)r * CAP2 + i] = s;
    }
}

// ---------------- final: sort exact candidates, softmax top-200, cumulative scatter ----------------
__global__ __launch_bounds__(256) void finalize3(
    const float* __restrict__ ev, const int* __restrict__ ci, const int* __restrict__ cc,
    const int* __restrict__ labels, float* __restrict__ out)
{
    __shared__ float sval[CAP];
    __shared__ int   sidx[CAP];
    __shared__ float cls[NCLS];
    __shared__ float s_sum;
    const int tid = threadIdx.x;
    const int r = blockIdx.x;
    const int M = min(cc[r], CAP);   // expected ~260 << 512

    for (int i = tid; i < CAP; i += 256) {
        if (i < M) { sval[i] = ev[(size_t)r * CAP2 + i]; sidx[i] = ci[(size_t)r * CAP2 + i]; }
        else { sval[i] = -FLT_MAX; sidx[i] = 0x7FFFFFFF; }
    }
    __syncthreads();

    // bitonic sort, descending by (val desc, idx asc)
    for (int k = 2; k <= CAP; k <<= 1)
        for (int j = k >> 1; j > 0; j >>= 1) {
            for (int i = tid; i < CAP; i += 256) {
                int l = i ^ j;
                if (l > i) {
                    float av = sval[i], bv2 = sval[l];
                    int ai = sidx[i], bi = sidx[l];
                    bool iGTl = (av > bv2) || (av == bv2 && ai < bi);
                    bool sw = ((i & k) == 0) ? (!iGTl) : iGTl;
                    if (sw) { sval[i] = bv2; sval[l] = av; sidx[i] = bi; sidx[l] = ai; }
                }
            }
            __syncthreads();
        }

    float mx = sval[0];
    if (tid == 0) s_sum = 0.f;
    __syncthreads();
    float part = 0.f;
    for (int i = tid; i < MAXK; i += 256) {
        float e = expf((sval[i] - mx) * INV_T);
        sval[i] = e;
        part += e;
    }
    atomicAdd(&s_sum, part);
    __syncthreads();
    float inv = 1.f / s_sum;
    for (int i = tid; i < MAXK; i += 256) {
        sval[i] *= inv;
        sidx[i] = labels[sidx[i]];
    }
    for (int c = tid; c < NCLS; c += 256) cls[c] = 0.f;
    __syncthreads();

    const int KS[4] = {10, 20, 100, 200};
    int prev = 0;
    for (int s = 0; s < 4; ++s) {
        for (int i = prev + tid; i < KS[s]; i += 256)
            atomicAdd(&cls[sidx[i]], sval[i]);
        __syncthreads();
        float* o = out + ((size_t)s * NROWS + r) * NCLS;
        for (int c = tid; c < NCLS; c += 256) o[c] = cls[c];
        __syncthreads();
        prev = KS[s];
    }
}

// ---------------- host launcher ----------------
extern "C" void kernel_launch(void* const* d_in, const int* in_sizes, int n_in,
                              void* d_out, int out_size, void* d_ws, size_t ws_size,
                              hipStream_t stream)
{
    const float* A = (const float*)d_in[0];       // [512,1024]
    const float* B = (const float*)d_in[1];       // [100000,1024]
    const int* labels = (const int*)d_in[2];      // [100000]
    float* out = (float*)d_out;                   // [4,512,1000] f32

    char* ws = (char*)d_ws;
    size_t off = 0;
    auto carve = [&](size_t bytes) -> void* {
        void* p = ws + off;
        off = (off + bytes + 255) & ~(size_t)255;
        return p;
    };
    unsigned short* Ab = (unsigned short*)carve((size_t)NROWS * DIM * 2);     // 1 MB
    int*   ci = (int*)carve((size_t)NROWS * CAP2 * 4);                        // 2 MB
    float* ev = (float*)carve((size_t)NROWS * CAP2 * 4);                      // 2 MB
    int*   cc = (int*)carve((size_t)NROWS * 4);
    unsigned short* simsb = (unsigned short*)carve((size_t)NROWS * NPAD * 2); // 102.8 MB

    // A -> bf16 (tiny)
    convert_bf16<<<128, 256, 0, stream>>>(A, Ab, (long long)NROWS * DIM);

    // full bf16 sims with write-side fused fp32->bf16 B conversion
    gemm_fused<<<4 * NTILE, 256, 0, stream>>>(Ab, B, simsb);

    // per-row top-200 superset via flat histogram + margin
    select_margin<<<NROWS, 512, 0, stream>>>(simsb, ci, cc);

    // exact fp32 recompute of survivors
    exact_refine<<<NROWS * 4, 256, 0, stream>>>(A, B, ci, cc, ev);

    // exact sort + softmax + scatter
    finalize3<<<NROWS, 256, 0, stream>>>(ev, ci, cc, labels, out);
}

// Round 10
// 391.733 us; speedup vs baseline: 1.0103x; 1.0103x over previous
//
#include <hip/hip_runtime.h>
#include <float.h>
#include <math.h>

#define NROWS 512
#define DIM 1024
#define NTRAIN 100000
#define MAXK 200
#define NCLS 1000
#define CAP 512          // finalize working set
#define CAP2 1024        // candidate list per row (expected ~260)
#define INV_T (1.0f/0.07f)
#define NKS (DIM/32)     // 32 K-steps of BK=32
#define NTILE 784        // ceil(100000/128)
#define NPAD (NTILE*128) // 100352 padded sims stride
#define MARGIN 3.0f      // ~20 sigma of bf16-RTZ sim error + storage ulp
#define HBINS 2048
#define HLO (-160.0f)
#define HSC 6.4f         // bins of width 0.15625 over [-160,160)

typedef short s16x8 __attribute__((ext_vector_type(8)));
typedef unsigned short u16x8 __attribute__((ext_vector_type(8)));
typedef unsigned int u32x4 __attribute__((ext_vector_type(4)));
typedef float f32x4 __attribute__((ext_vector_type(4)));

__device__ __forceinline__ void gl_lds16(const void* g, void* l) {
    __builtin_amdgcn_global_load_lds(
        (const __attribute__((address_space(1))) unsigned int*)g,
        (__attribute__((address_space(3))) unsigned int*)l, 16, 0, 0);
}
__device__ __forceinline__ unsigned short f2bf(float x) {   // RTNE
    unsigned u = __float_as_uint(x);
    return (unsigned short)((u + 0x7FFFu + ((u >> 16) & 1u)) >> 16);
}
__device__ __forceinline__ float bf2f(unsigned short b) {
    return __uint_as_float(((unsigned)b) << 16);
}

// ---------------- fp32 -> bf16 (A only; B fused into GEMM) ----------------
__global__ __launch_bounds__(256) void convert_bf16(
    const float* __restrict__ in, unsigned short* __restrict__ out, long long n)
{
    long long i0 = ((long long)blockIdx.x * 256 + threadIdx.x) * 8;
    long long stride = (long long)gridDim.x * 2048;
    for (long long i = i0; i < n; i += stride) {
        float4 v0 = *reinterpret_cast<const float4*>(&in[i]);
        float4 v1 = *reinterpret_cast<const float4*>(&in[i + 4]);
        u16x8 o;
        o[0] = f2bf(v0.x); o[1] = f2bf(v0.y); o[2] = f2bf(v0.z); o[3] = f2bf(v0.w);
        o[4] = f2bf(v1.x); o[5] = f2bf(v1.y); o[6] = f2bf(v1.z); o[7] = f2bf(v1.w);
        *reinterpret_cast<u16x8*>(&out[i]) = o;
    }
}

// ---------------- fused GEMM: r7's drain-then-issue depth-2 + r8's read-side B ----------------
// 128x128 tile, BK=32, 4 waves. 3 bufs x (A bf16 8KB + B fp32 16KB) = 72KB -> 2 blocks/CU.
// Step T: vmcnt(6) drains group T (issued at T-2; leaves group T+1 in flight across the
// barrier) -> s_barrier -> issue group T+2 -> ds_read + MFMA. 2 full steps of load flight.
// A layout (0-conflict, r5-r7): chunk = rr*4 + (q ^ ((rr>>1)&3)).
// B fp32 layout (r8): chunk = rr*8 + (q ^ (rr&7)); read 2x b128 + 4 v_perm RTZ per frag.
__global__ __launch_bounds__(256) void gemm_fused(
    const unsigned short* __restrict__ Ab, const float* __restrict__ B,
    unsigned short* __restrict__ simsb)
{
    __shared__ __align__(16) char sm[3][24576];   // [buf][A 8KB | B 16KB]
    const int tid = threadIdx.x;
    const int lane = tid & 63;
    const int wave = tid >> 6;

    // bijective XCD swizzle (grid % 8 == 0), m-tile fastest for B-panel L2 reuse
    const int nwg = gridDim.x;
    const int wg = (blockIdx.x & 7) * (nwg >> 3) + (blockIdx.x >> 3);
    const int mt = wg & 3, nt = wg >> 2;
    const int m0 = mt * 128, n0 = nt * 128;
    const int wm = wave >> 1, wn = wave & 1;

    // A staging: 512 chunks of 16B; instr i covers chunks wave*64 + i*256 + lane
    size_t gA[2];
    #pragma unroll
    for (int i = 0; i < 2; ++i) {
        int c = wave * 64 + i * 256 + lane;
        int rr = c >> 2, q = c & 3;
        int slot = q ^ ((rr >> 1) & 3);
        gA[i] = (size_t)(m0 + rr) * DIM + slot * 8;   // bf16 elements
    }
    const int ldsA0 = (wave * 64) * 16;
    const int ldsA1 = (wave * 64 + 256) * 16;

    // B staging (fp32): 1024 chunks of 16B; instr i covers chunks wave*256 + i*64 + lane
    size_t gB[4];
    #pragma unroll
    for (int i = 0; i < 4; ++i) {
        int c = wave * 256 + i * 64 + lane;
        int rr = c >> 3, q = c & 7;
        int slot = q ^ (rr & 7);
        int brow = n0 + rr;
        if (brow > NTRAIN - 1) brow = NTRAIN - 1;     // pad cols clamp (never selected)
        gB[i] = (size_t)brow * DIM + slot * 4;        // fp32 elements
    }
    const int ldsB[4] = { 8192 + (wave * 256) * 16, 8192 + (wave * 256 + 64) * 16,
                          8192 + (wave * 256 + 128) * 16, 8192 + (wave * 256 + 192) * 16 };

    f32x4 acc[4][4] = {};

    auto stage = [&](int b, int k0) {
        char* base = &sm[b][0];
        gl_lds16(Ab + gA[0] + k0, base + ldsA0);
        gl_lds16(Ab + gA[1] + k0, base + ldsA1);
        #pragma unroll
        for (int i = 0; i < 4; ++i)
            gl_lds16(B + gB[i] + k0, base + ldsB[i]);
    };

    const int qq = lane >> 4;     // k-quarter
    const int r16 = lane & 15;

    // prologue: groups 0 and 1 in flight
    stage(0, 0);
    stage(1, 32);

    for (int t = 0; t < NKS; ++t) {
        // drain group t (issued at t-2); leave group t+1's 6 loads in flight
        if (t + 1 < NKS) {
            asm volatile("s_waitcnt vmcnt(6)" ::: "memory");
        } else {
            asm volatile("s_waitcnt vmcnt(0)" ::: "memory");
        }
        __builtin_amdgcn_s_barrier();
        __builtin_amdgcn_sched_barrier(0);

        if (t + 2 < NKS) stage((t + 2) % 3, (t + 2) * 32);   // issue AFTER the wait

        const char* sa = &sm[t % 3][0];
        const char* sbB = &sm[t % 3][8192];

        // B frags: 2x b128 fp32 reads + 4 v_perm RTZ pack per frag
        s16x8 bv[4];
        #pragma unroll
        for (int n = 0; n < 4; ++n) {
            int rr = wn * 64 + n * 16 + r16;
            const char* rowb = sbB + (rr * 8) * 16;
            int c0 = (2 * qq) ^ (rr & 7);
            int c1 = (2 * qq + 1) ^ (rr & 7);
            u32x4 fa = *reinterpret_cast<const u32x4*>(rowb + c0 * 16);
            u32x4 fb = *reinterpret_cast<const u32x4*>(rowb + c1 * 16);
            unsigned w0 = __builtin_amdgcn_perm(fa[1], fa[0], 0x07060302u);
            unsigned w1 = __builtin_amdgcn_perm(fa[3], fa[2], 0x07060302u);
            unsigned w2 = __builtin_amdgcn_perm(fb[1], fb[0], 0x07060302u);
            unsigned w3 = __builtin_amdgcn_perm(fb[3], fb[2], 0x07060302u);
            u32x4 packed = { w0, w1, w2, w3 };
            bv[n] = __builtin_bit_cast(s16x8, packed);
        }
        #pragma unroll
        for (int m = 0; m < 4; ++m) {
            int rr = wm * 64 + m * 16 + r16;
            int cch = rr * 4 + (qq ^ ((rr >> 1) & 3));
            s16x8 av = *reinterpret_cast<const s16x8*>(sa + cch * 16);
            #pragma unroll
            for (int n = 0; n < 4; ++n)
                acc[m][n] = __builtin_amdgcn_mfma_f32_16x16x32_bf16(av, bv[n], acc[m][n], 0, 0, 0);
        }
        // no trailing barrier: buf[t%3] is only overwritten by group t+3, issued at
        // step t+1 AFTER barrier(t+1) — by which point every wave's step-t LDS reads
        // have been consumed by its MFMAs (in-order issue before barrier arrival).
    }

    // epilogue: C/D layout col=lane&15, row=(lane>>4)*4+reg; bf16 store
    const int q4 = (lane >> 4) * 4;
    const int cL = lane & 15;
    #pragma unroll
    for (int m = 0; m < 4; ++m)
        #pragma unroll
        for (int j = 0; j < 4; ++j) {
            int orow = m0 + wm * 64 + m * 16 + q4 + j;
            unsigned short* dst = simsb + (size_t)orow * NPAD + n0 + wn * 64 + cL;
            #pragma unroll
            for (int n = 0; n < 4; ++n)
                dst[n * 16] = f2bf(acc[m][n][j]);
        }
}

// ---------------- per-row: flat histogram -> threshold-with-margin -> append ----------------
__global__ __launch_bounds__(512) void select_margin(
    const unsigned short* __restrict__ simsb, int* __restrict__ ci, int* __restrict__ cc)
{
    __shared__ int hist[4][HBINS];   // 32KB, 4 replicas to cut atomic collisions
    __shared__ float s_L;
    __shared__ int s_cnt;
    const int tid = threadIdx.x;
    const int r = blockIdx.x;
    const unsigned short* srow = simsb + (size_t)r * NPAD;

    for (int i = tid; i < 4 * HBINS; i += 512) hist[i >> 11][i & (HBINS - 1)] = 0;
    if (tid == 0) s_cnt = 0;
    __syncthreads();

    // NTRAIN % 8 == 0: loops never touch pad cols
    for (int i = tid * 8; i < NTRAIN; i += 4096) {
        u16x8 v = *reinterpret_cast<const u16x8*>(&srow[i]);
        #pragma unroll
        for (int j = 0; j < 8; ++j) {
            int b = (int)fminf(fmaxf((bf2f(v[j]) - HLO) * HSC, 0.0f), 2047.0f);
            atomicAdd(&hist[tid & 3][b], 1);
        }
    }
    __syncthreads();
    for (int i = tid; i < HBINS; i += 512)
        hist[0][i] += hist[1][i] + hist[2][i] + hist[3][i];
    __syncthreads();
    if (tid == 0) {
        int cum = 0, b = HBINS - 1;
        for (; b > 0; --b) { if (cum + hist[0][b] >= MAXK) break; cum += hist[0][b]; }
        s_L = HLO + (float)b / HSC - MARGIN;   // bin lower edge minus margin
    }
    __syncthreads();
    const float Lv = s_L;

    for (int i = tid * 8; i < NTRAIN; i += 4096) {
        u16x8 v = *reinterpret_cast<const u16x8*>(&srow[i]);
        #pragma unroll
        for (int j = 0; j < 8; ++j) {
            if (bf2f(v[j]) >= Lv) {
                int p = atomicAdd(&s_cnt, 1);
                if (p < CAP2) ci[(size_t)r * CAP2 + p] = i + j;
            }
        }
    }
    __syncthreads();
    if (tid == 0) cc[r] = min(s_cnt, CAP2);
}

// ---------------- exact fp32 recompute of candidate dots ----------------
__global__ __launch_bounds__(256) void exact_refine(
    const float* __restrict__ A, const float* __restrict__ B,
    const int* __restrict__ ci, const int* __restrict__ cc, float* __restrict__ ev)
{
    __shared__ float sa[DIM];
    const int tid = threadIdx.x;
    const int r = blockIdx.x >> 2;
    const int part = blockIdx.x & 3;
    *reinterpret_cast<float4*>(&sa[tid * 4]) =
        *reinterpret_cast<const float4*>(&A[(size_t)r * DIM + tid * 4]);
    __syncthreads();
    const int lane = tid & 63;
    const int wave = tid >> 6;
    const int w = part * 4 + wave;
    const int M = min(cc[r], CAP2);

    for (int i = w; i < M; i += 16) {
        int idx = ci[(size_t)r * CAP2 + i];
        const float* brow = B + (size_t)idx * DIM;
        float s = 0.f;
        #pragma unroll
        for (int j = 0; j < 4; ++j) {
            float4 bvv = *reinterpret_cast<const float4*>(&brow[j * 256 + lane * 4]);
            float4 avv = *reinterpret_cast<const float4*>(&sa[j * 256 + lane * 4]);
            s = fmaf(avv.x, bvv.x, s);
            s = fmaf(avv.y, bvv.y, s);
            s = fmaf(avv.z, bvv.z, s);
            s = fmaf(avv.w, bvv.w, s);
        }
        #pragma unroll
        for (int m = 32; m >= 1; m >>= 1) s += __shfl_xor(s, m);
        if (lane == 0) ev[(size_t)r * CAP2 + i] = s;
    }
}

// ---------------- final: sort exact candidates, softmax top-200, cumulative scatter ----------------
__global__ __launch_bounds__(256) void finalize3(
    const float* __restrict__ ev, const int* __restrict__ ci, const int* __restrict__ cc,
    const int* __restrict__ labels, float* __restrict__ out)
{
    __shared__ float sval[CAP];
    __shared__ int   sidx[CAP];
    __shared__ float cls[NCLS];
    __shared__ float s_sum;
    const int tid = threadIdx.x;
    const int r = blockIdx.x;
    const int M = min(cc[r], CAP);   // expected ~260 << 512

    for (int i = tid; i < CAP; i += 256) {
        if (i < M) { sval[i] = ev[(size_t)r * CAP2 + i]; sidx[i] = ci[(size_t)r * CAP2 + i]; }
        else { sval[i] = -FLT_MAX; sidx[i] = 0x7FFFFFFF; }
    }
    __syncthreads();

    // bitonic sort, descending by (val desc, idx asc)
    for (int k = 2; k <= CAP; k <<= 1)
        for (int j = k >> 1; j > 0; j >>= 1) {
            for (int i = tid; i < CAP; i += 256) {
                int l = i ^ j;
                if (l > i) {
                    float av = sval[i], bv2 = sval[l];
                    int ai = sidx[i], bi = sidx[l];
                    bool iGTl = (av > bv2) || (av == bv2 && ai < bi);
                    bool sw = ((i & k) == 0) ? (!iGTl) : iGTl;
                    if (sw) { sval[i] = bv2; sval[l] = av; sidx[i] = bi; sidx[l] = ai; }
                }
            }
            __syncthreads();
        }

    float mx = sval[0];
    if (tid == 0) s_sum = 0.f;
    __syncthreads();
    float part = 0.f;
    for (int i = tid; i < MAXK; i += 256) {
        float e = expf((sval[i] - mx) * INV_T);
        sval[i] = e;
        part += e;
    }
    atomicAdd(&s_sum, part);
    __syncthreads();
    float inv = 1.f / s_sum;
    for (int i = tid; i < MAXK; i += 256) {
        sval[i] *= inv;
        sidx[i] = labels[sidx[i]];
    }
    for (int c = tid; c < NCLS; c += 256) cls[c] = 0.f;
    __syncthreads();

    const int KS[4] = {10, 20, 100, 200};
    int prev = 0;
    for (int s = 0; s < 4; ++s) {
        for (int i = prev + tid; i < KS[s]; i += 256)
            atomicAdd(&cls[sidx[i]], sval[i]);
        __syncthreads();
        float* o = out + ((size_t)s * NROWS + r) * NCLS;
        for (int c = tid; c < NCLS; c += 256) o[c] = cls[c];
        __syncthreads();
        prev = KS[s];
    }
}

// ---------------- host launcher ----------------
extern "C" void kernel_launch(void* const* d_in, const int* in_sizes, int n_in,
                              void* d_out, int out_size, void* d_ws, size_t ws_size,
                              hipStream_t stream)
{
    const float* A = (const float*)d_in[0];       // [512,1024]
    const float* B = (const float*)d_in[1];       // [100000,1024]
    const int* labels = (const int*)d_in[2];      // [100000]
    float* out = (float*)d_out;                   // [4,512,1000] f32

    char* ws = (char*)d_ws;
    size_t off = 0;
    auto carve = [&](size_t bytes) -> void* {
        void* p = ws + off;
        off = (off + bytes + 255) & ~(size_t)255;
        return p;
    };
    unsigned short* Ab = (unsigned short*)carve((size_t)NROWS * DIM * 2);     // 1 MB
    int*   ci = (int*)carve((size_t)NROWS * CAP2 * 4);                        // 2 MB
    float* ev = (float*)carve((size_t)NROWS * CAP2 * 4);                      // 2 MB
    int*   cc = (int*)carve((size_t)NROWS * 4);
    unsigned short* simsb = (unsigned short*)carve((size_t)NROWS * NPAD * 2); // 102.8 MB

    // A -> bf16 (tiny)
    convert_bf16<<<128, 256, 0, stream>>>(A, Ab, (long long)NROWS * DIM);

    // full bf16 sims with read-side fused fp32->bf16 B conversion
    gemm_fused<<<4 * NTILE, 256, 0, stream>>>(Ab, B, simsb);

    // per-row top-200 superset via flat histogram + margin
    select_margin<<<NROWS, 512, 0, stream>>>(simsb, ci, cc);

    // exact fp32 recompute of survivors
    exact_refine<<<NROWS * 4, 256, 0, stream>>>(A, B, ci, cc, ev);

    // exact sort + softmax + scatter
    finalize3<<<NROWS, 256, 0, stream>>>(ev, ci, cc, labels, out);
}